// Round 15
// baseline (205.700 us; speedup 1.0000x reference)
//
#include <hip/hip_runtime.h>

// Problem constants
#define BATCH 16
#define CH 64          // EMBEDDING_DIM
#define HW 4096        // 64*64
#define NPIX 65536     // BATCH*HW
#define KCODES 512
#define DDIM 64
#define NELEM 4194304  // NPIX*CH

// d_out layout (float32): [z_q_st: NELEM][loss: 1][ppl: 1][indices: NPIX]
#define OUT_LOSS 4194304
#define OUT_PPL  4194305
#define OUT_IDX  4194306

// bf16 gap-error: rms ~4e-5 => 2.2e-4 is ~5.5 sigma; covers np fp32 quantization (7.6e-6)
#define MARGIN 2.2e-4f

typedef short bf16x8 __attribute__((ext_vector_type(8)));
typedef float f32x4  __attribute__((ext_vector_type(4)));

__device__ __forceinline__ float rnd(float s) {   // block fp-contract (numpy-exact squares)
    asm volatile("" : "+v"(s));
    return s;
}
__device__ __forceinline__ short f2bf(float f) {  // RNE fp32->bf16
    unsigned u = __builtin_bit_cast(unsigned, f);
    unsigned r = (u + 0x7fffu + ((u >> 16) & 1u)) >> 16;
    return (short)r;
}

// -------------------- fused distance/argmin + epilogue kernel --------------------
// 512 thr = 8 waves x 16 px = 128 px/block. Grid 512 -> 2 blocks/CU, all resident.
// Codebook converted emb->bf16-fragment-layout IN-BLOCK (no prep kernel, no global
// round-trip). Two barriers per block. min/2nd-min via v_med3_f32 (R14: -10 us).
__global__ __launch_bounds__(512, 4) void k_dist(
        const float* __restrict__ z_e, const float* __restrict__ emb,
        int* __restrict__ idx, int* __restrict__ glist, int* __restrict__ nflag,
        int* __restrict__ counts, float* __restrict__ slots,
        float* __restrict__ out) {
    __shared__ bf16x8 Bs[4096];      // 64 KB: full codebook, fragment order
    __shared__ float e2s[512];
    __shared__ int   hist[512];
    __shared__ int   flist[128];
    __shared__ int   fcnt, fbase;

    int t = threadIdx.x;
    int pxbase = blockIdx.x * 128;
    int batch = pxbase >> 12;
    int p0 = pxbase & 4095;
    const float* zb = z_e + (size_t)batch * (CH * HW) + p0;

    // stage B in-block: fragment entry gid = tn*128 + chunk*64 + (q<<4|i);
    //   code = tn*16+i, k = chunk*32 + q*8 + j  (layout HW-verified R4)
    #pragma unroll
    for (int i8 = 0; i8 < 8; ++i8) {
        int gid = i8 * 512 + t;
        int tn = gid >> 7, rem = gid & 127;
        int chunk = (rem >> 6) & 1, q = (rem >> 4) & 3, ii = rem & 15;
        const float* src = emb + (tn * 16 + ii) * DDIM + chunk * 32 + q * 8;
        float4 v0 = *(const float4*)src;
        float4 v1 = *(const float4*)(src + 4);
        bf16x8 h;
        h[0] = f2bf(v0.x); h[1] = f2bf(v0.y); h[2] = f2bf(v0.z); h[3] = f2bf(v0.w);
        h[4] = f2bf(v1.x); h[5] = f2bf(v1.y); h[6] = f2bf(v1.z); h[7] = f2bf(v1.w);
        Bs[gid] = h;
    }
    // e2 in-block: numpy pairwise (identical rounding to the verified prep)
    {
        const float* row = emb + t * DDIM;
        float r[8];
        #pragma unroll
        for (int j = 0; j < 8; ++j) { float v = row[j]; r[j] = rnd(v * v); }
        #pragma unroll
        for (int m = 1; m < 8; ++m)
            #pragma unroll
            for (int j = 0; j < 8; ++j) { float v = row[8 * m + j]; r[j] += rnd(v * v); }
        e2s[t] = ((r[0] + r[1]) + (r[2] + r[3])) + ((r[4] + r[5]) + (r[6] + r[7]));
    }
    hist[t] = 0;
    if (t == 0) fcnt = 0;

    int w = t >> 6, lane = t & 63, col = lane & 15, quad = lane >> 4;
    int px = w * 16 + col;

    // A-frags direct from global: px = w*16+col, k = chunk*32 + quad*8 + j
    bf16x8 a0, a1;
    #pragma unroll
    for (int j = 0; j < 8; ++j) {
        a0[j] = f2bf(zb[(quad * 8 + j) * HW + px]);
        a1[j] = f2bf(zb[(32 + quad * 8 + j) * HW + px]);
    }
    __syncthreads();   // barrier #1

    float m1[4], m2[4];
    int   i1[4];
    #pragma unroll
    for (int r = 0; r < 4; ++r) { m1[r] = 1e30f; m2[r] = 1e30f; i1[r] = 0; }

    // barrier-free N loop: pure ds_read_b128 + MFMA + med3-select
    #pragma unroll 4
    for (int tn = 0; tn < 32; ++tn) {
        bf16x8 c0 = Bs[tn * 128 + lane];
        bf16x8 c1 = Bs[tn * 128 + 64 + lane];
        float e2v = e2s[tn * 16 + col];
        int n = tn * 16 + col;
        f32x4 acc = {0.f, 0.f, 0.f, 0.f};
        acc = __builtin_amdgcn_mfma_f32_16x16x32_bf16(a0, c0, acc, 0, 0, 0);
        acc = __builtin_amdgcn_mfma_f32_16x16x32_bf16(a1, c1, acc, 0, 0, 0);
        #pragma unroll
        for (int r = 0; r < 4; ++r) {
            float d = fmaf(-2.0f, acc[r], e2v);
            // m2' = med3(d,m1,m2): exact 2nd-min update (R14-verified)
            m2[r] = __builtin_amdgcn_fmed3f(d, m1[r], m2[r]);
            bool c = d < m1[r];
            m1[r] = fminf(d, m1[r]);
            i1[r] = c ? n : i1[r];   // tie keeps earlier n = np first-occurrence
        }
    }

    // merge the 16 cols (xor butterfly -> every lane holds result for px quad*4+r)
    #pragma unroll
    for (int off = 1; off < 16; off <<= 1) {
        #pragma unroll
        for (int r = 0; r < 4; ++r) {
            float om1 = __shfl_xor(m1[r], off);
            float om2 = __shfl_xor(m2[r], off);
            int   oi  = __shfl_xor(i1[r], off);
            if (om1 < m1[r] || (om1 == m1[r] && oi < i1[r])) {
                m2[r] = fminf(m1[r], om2);
                m1[r] = om1;
                i1[r] = oi;
            } else {
                m2[r] = fminf(m2[r], om1);
            }
        }
    }

    // per-pixel outputs: idx, out-idx, LDS histogram + LDS flag list (no global atomics)
    if (col == 0) {
        #pragma unroll
        for (int r = 0; r < 4; ++r) {
            int g = pxbase + w * 16 + quad * 4 + r;
            idx[g] = i1[r];
            out[OUT_IDX + g] = (float)i1[r];
            atomicAdd(&hist[i1[r]], 1);
            if (m2[r] - m1[r] < MARGIN) {
                int pos = atomicAdd(&fcnt, 1);   // LDS atomic
                flist[pos] = g;
            }
        }
    }

    // fused epilogue: z_q_st for this wave's 16 px (z_e is L1/L3-hot), + loss partial
    int q4 = lane & 3;
    int bidx[4];
    #pragma unroll
    for (int j = 0; j < 4; ++j) bidx[j] = __shfl(i1[j], q4 << 4);  // best for px q4*4+j
    const float* zw = zb + w * 16;
    float* ow = out + (size_t)batch * (CH * HW) + p0 + w * 16;
    float lsum = 0.0f;
    #pragma unroll
    for (int it = 0; it < 4; ++it) {
        int c = it * 16 + (lane >> 2);
        float4 ze = *(const float4*)(zw + c * HW + q4 * 4);
        float d0 = emb[bidx[0] * DDIM + c] - ze.x;
        float d1 = emb[bidx[1] * DDIM + c] - ze.y;
        float d2 = emb[bidx[2] * DDIM + c] - ze.z;
        float d3 = emb[bidx[3] * DDIM + c] - ze.w;
        float4 o = {ze.x + d0, ze.y + d1, ze.z + d2, ze.w + d3};
        *(float4*)(ow + c * HW + q4 * 4) = o;
        lsum = lsum + d0 * d0 + d1 * d1 + d2 * d2 + d3 * d3;
    }
    #pragma unroll
    for (int off = 32; off; off >>= 1) lsum += __shfl_down(lsum, off);
    if (lane == 0) atomicAdd(&slots[((blockIdx.x * 8 + w) & 63) * 16], lsum);

    // barrier #2, then flush histogram + flag list (one returning atomic per block)
    __syncthreads();
    int v0 = hist[t];
    if (v0) atomicAdd(&counts[t], v0);
    if (t == 0) fbase = atomicAdd(nflag, fcnt);
    __syncthreads();
    if (t < fcnt) glist[fbase + t] = flist[t];
}

// -------------------- refine + fused final: full codebook in LDS ------------------
// Ps (verified fragment layout) built IN-BLOCK from emb; per-lane e2 from Ps with
// the identical numpy-pairwise rounding. Hot loop byte-identical to R9-R14. The
// LAST block (device-scope done counter) computes loss/perplexity via atomic reads
// (coherence-safe across XCDs).  __launch_bounds__(256) is LOAD-BEARING (R5).
__global__ __launch_bounds__(256) void k_refine(
        const float* __restrict__ z_e, const float* __restrict__ emb,
        const int* __restrict__ glist, const int* __restrict__ nflag,
        int* __restrict__ idx, int* __restrict__ counts,
        float* __restrict__ slots, int* __restrict__ done,
        float* __restrict__ out) {
    __shared__ float4 Ps[8192];      // 128 KB: transposed codebook, fragment order
    __shared__ float  xs[4][64];     // one x-vector slot per wave
    __shared__ int    islast;
    __shared__ float  ls[4];
    __shared__ float  lsumf;

    int t = threadIdx.x;
    int w = t >> 6, lane = t & 63;
    int n = nflag[0];

    // stage Ps in-block: Ps[(kk*16+c4)*64 + ln] = emb[ln*8+kk][c4*4..+3]
    #pragma unroll
    for (int it = 0; it < 32; ++it) {
        int e = it * 256 + t;
        int ln = e & 63, c4 = (e >> 6) & 15, kk = e >> 10;
        Ps[e] = *(const float4*)(emb + (ln * 8 + kk) * DDIM + c4 * 4);
    }
    __syncthreads();

    // per-lane e2 for codes lane*8+kk from Ps (numpy pairwise: rA=j0..3, rB=j4..7,
    // m = c4>>1 ascending — identical rounding order to the verified prep)
    float e2v[8];
    #pragma unroll
    for (int kk = 0; kk < 8; ++kk) {
        float4 ev = Ps[(kk * 16 + 0) * 64 + lane];
        float rA0 = rnd(ev.x * ev.x), rA1 = rnd(ev.y * ev.y);
        float rA2 = rnd(ev.z * ev.z), rA3 = rnd(ev.w * ev.w);
        ev = Ps[(kk * 16 + 1) * 64 + lane];
        float rB0 = rnd(ev.x * ev.x), rB1 = rnd(ev.y * ev.y);
        float rB2 = rnd(ev.z * ev.z), rB3 = rnd(ev.w * ev.w);
        #pragma unroll
        for (int m = 1; m < 8; ++m) {
            ev = Ps[(kk * 16 + 2 * m) * 64 + lane];
            rA0 += rnd(ev.x * ev.x); rA1 += rnd(ev.y * ev.y);
            rA2 += rnd(ev.z * ev.z); rA3 += rnd(ev.w * ev.w);
            ev = Ps[(kk * 16 + 2 * m + 1) * 64 + lane];
            rB0 += rnd(ev.x * ev.x); rB1 += rnd(ev.y * ev.y);
            rB2 += rnd(ev.z * ev.z); rB3 += rnd(ev.w * ev.w);
        }
        e2v[kk] = ((rA0 + rA1) + (rA2 + rA3)) + ((rB0 + rB1) + (rB2 + rB3));
    }

    int wid = blockIdx.x * 4 + w;
    for (int j = wid; j < n; j += 1024) {
        int g = glist[j];                 // wave-uniform scalar load
        int b = g >> 12, p = g & 4095;
        xs[w][lane] = z_e[(size_t)b * (CH * HW) + (size_t)lane * HW + p];
        __threadfence_block();            // wave-lockstep LDS visibility

        const float* xr = xs[w];
        // numpy pairwise ||x||^2 (8 accumulators + tree), broadcast LDS reads
        float r[8];
        #pragma unroll
        for (int jj = 0; jj < 8; ++jj) { float v = xr[jj]; r[jj] = rnd(v * v); }
        #pragma unroll
        for (int mm = 1; mm < 8; ++mm)
            #pragma unroll
            for (int jj = 0; jj < 8; ++jj) { float v = xr[8 * mm + jj]; r[jj] += rnd(v * v); }
        float x2 = ((r[0] + r[1]) + (r[2] + r[3])) + ((r[4] + r[5]) + (r[6] + r[7]));

        float bestd = INFINITY;
        int besti = 1 << 30;
        #pragma unroll
        for (int kk = 0; kk < 8; ++kk) {
            double d0 = 0.0, d1 = 0.0, d2 = 0.0, d3 = 0.0;
            #pragma unroll
            for (int c4 = 0; c4 < 16; ++c4) {
                float4 xq = *(const float4*)&xr[c4 * 4];         // broadcast
                float4 ev = Ps[(kk * 16 + c4) * 64 + lane];      // per-lane, conflict-free
                d0 = fma((double)xq.x, (double)ev.x, d0);
                d1 = fma((double)xq.y, (double)ev.y, d1);
                d2 = fma((double)xq.z, (double)ev.z, d2);
                d3 = fma((double)xq.w, (double)ev.w, d3);
            }
            float dotf = (float)((d0 + d1) + (d2 + d3));  // ~= sgemm dot
            float tt = x2 + e2v[kk];                      // np fp32 add
            float d = tt - 2.0f * dotf;                   // np fp32 sub
            if (d < bestd) { bestd = d; besti = lane * 8 + kk; }
        }
        #pragma unroll
        for (int off = 32; off; off >>= 1) {
            float od = __shfl_down(bestd, off);
            int   oi = __shfl_down(besti, off);
            if (od < bestd || (od == bestd && oi < besti)) { bestd = od; besti = oi; }
        }
        besti = __shfl(besti, 0);

        int old = idx[g];
        if (besti != old) {
            // patch z_q_st row (lane c = channel c), loss delta, counts, index
            float xc = xr[lane];
            float qn = emb[besti * DDIM + lane];
            float qo = emb[old * DDIM + lane];
            float dn = qn - xc, dold = qo - xc;
            out[(size_t)b * (CH * HW) + (size_t)lane * HW + p] = xc + dn;
            float delta = dn * dn - dold * dold;
            #pragma unroll
            for (int off = 32; off; off >>= 1) delta += __shfl_down(delta, off);
            if (lane == 0) {
                atomicAdd(&slots[(wid & 63) * 16], delta);
                atomicAdd(&counts[old], -1);
                atomicAdd(&counts[besti], 1);
                idx[g] = besti;
                out[OUT_IDX + g] = (float)besti;
            }
        }
    }

    // ---- last-block finisher: loss + perplexity ----
    __syncthreads();
    if (t == 0) {
        __threadfence();
        int d = atomicAdd(done, 1);
        islast = (d == (int)gridDim.x - 1);
    }
    __syncthreads();
    if (!islast) return;

    // atomic reads (device-coherent) of counts/slots written by other blocks
    float term = 0.0f;
    #pragma unroll
    for (int h = 0; h < 2; ++h) {
        int c = h * 256 + t;
        float cnt = (float)atomicAdd(&counts[c], 0);
        float pb = cnt * (1.0f / 65536.0f);
        term += pb * logf(pb + 1e-10f);
    }
    #pragma unroll
    for (int off = 32; off; off >>= 1) term += __shfl_down(term, off);
    if (lane == 0) ls[w] = term;
    if (w == 0) {
        float s2 = atomicAdd(&slots[lane * 16], 0.0f);
        #pragma unroll
        for (int off = 32; off; off >>= 1) s2 += __shfl_down(s2, off);
        if (lane == 0) lsumf = s2;
    }
    __syncthreads();
    if (t == 0) {
        float s = ls[0] + ls[1] + ls[2] + ls[3];
        out[OUT_PPL]  = expf(-s);
        out[OUT_LOSS] = 0.25f * (lsumf / (float)NELEM);
    }
}

extern "C" void kernel_launch(void* const* d_in, const int* in_sizes, int n_in,
                              void* d_out, int out_size, void* d_ws, size_t ws_size,
                              hipStream_t stream) {
    const float* z_e = (const float*)d_in[0];
    const float* emb = (const float*)d_in[1];
    float* out = (float*)d_out;
    char* ws = (char*)d_ws;

    // ws layout
    int*   idx    = (int*)(ws);              // 65536 ints   [0, 262144)
    int*   glist  = (int*)(ws + 262144);     // 65536 ints   [262144, 524288)
    int*   nflag  = (int*)(ws + 524288);     // 1 int (+pad) [524288, 524352)
    int*   counts = (int*)(ws + 524352);     // 512 ints     [524352, 526400)
    float* slots  = (float*)(ws + 526400);   // 64 x 16 floats [526400, 530496)
    int*   done   = (int*)(ws + 530496);     // 1 int

    // zero nflag + counts + slots + done (ws is poisoned 0xAA before every launch)
    hipMemsetAsync(ws + 524288, 0, 530560 - 524288, stream);

    k_dist<<<NPIX / 128, 512, 0, stream>>>(z_e, emb, idx, glist, nflag, counts, slots, out);
    k_refine<<<256, 256, 0, stream>>>(z_e, emb, glist, nflag, idx, counts, slots, done, out);
}

// Round 16
// 130.793 us; speedup vs baseline: 1.5727x; 1.5727x over previous
//
#include <hip/hip_runtime.h>

// Problem constants
#define BATCH 16
#define CH 64          // EMBEDDING_DIM
#define HW 4096        // 64*64
#define NPIX 65536     // BATCH*HW
#define KCODES 512
#define DDIM 64
#define NELEM 4194304  // NPIX*CH

// d_out layout (float32): [z_q_st: NELEM][loss: 1][ppl: 1][indices: NPIX]
#define OUT_LOSS 4194304
#define OUT_PPL  4194305
#define OUT_IDX  4194306

// bf16 gap-error: rms ~4e-5 => 2.2e-4 is ~5.5 sigma; covers np fp32 quantization (7.6e-6)
#define MARGIN 2.2e-4f

typedef short bf16x8 __attribute__((ext_vector_type(8)));
typedef float f32x4  __attribute__((ext_vector_type(4)));

__device__ __forceinline__ float rnd(float s) {   // block fp-contract (numpy-exact squares)
    asm volatile("" : "+v"(s));
    return s;
}
__device__ __forceinline__ short f2bf(float f) {  // RNE fp32->bf16
    unsigned u = __builtin_bit_cast(unsigned, f);
    unsigned r = (u + 0x7fffu + ((u >> 16) & 1u)) >> 16;
    return (short)r;
}
// direct global->LDS DMA, 16B/lane (dest must be wave-uniform base + lane*16)
__device__ __forceinline__ void gl_lds16(const void* g, void* l) {
    __builtin_amdgcn_global_load_lds(
        (const __attribute__((address_space(1))) unsigned*)g,
        (__attribute__((address_space(3))) unsigned*)l, 16, 0, 0);
}

// -------------------- prep: e2 + fragment bf16 codebook + fp32 transpose + zeroing ---
// SEPARATE prep kernel is LOAD-BEARING (R12/R15: fusing it in-block replicates the
// conversion 512x with 64-lines-per-instr access patterns; R15 cost +77 us).
// Bh packing: entry = tn*128 + chunk*64 + lane, lane=(q<<4)|i  (HW-verified R4).
// P4 packing: P4[(kk*16+c4)*64 + lane] = emb[lane*8+kk][c4*4..+3]
// Block 0 also zeroes nflag/counts/slots/done (replaces the hipMemsetAsync dispatch).
__global__ void k_prep(const float* __restrict__ emb, float* __restrict__ e2,
                       bf16x8* __restrict__ Bh, float4* __restrict__ P4,
                       int* __restrict__ zws) {
    if (blockIdx.x == 0) {
        #pragma unroll
        for (int i = threadIdx.x; i < 1568; i += 256) zws[i] = 0;  // 6272 B of accumulators
    }
    int gid = blockIdx.x * 256 + threadIdx.x;
    if (gid < 4096) {
        int tn = gid >> 7, rem = gid & 127;
        int chunk = (rem >> 6) & 1, q = (rem >> 4) & 3, i = rem & 15;
        int code = tn * 16 + i;
        const float* src = emb + code * DDIM + chunk * 32 + q * 8;
        bf16x8 h;
        #pragma unroll
        for (int j = 0; j < 8; ++j) h[j] = f2bf(src[j]);
        Bh[gid] = h;
    } else if (gid < 4608) {
        int k = gid - 4096;
        const float* row = emb + k * DDIM;
        float r[8];
        #pragma unroll
        for (int j = 0; j < 8; ++j) { float v = row[j]; r[j] = rnd(v * v); }
        #pragma unroll
        for (int m = 1; m < 8; ++m)
            #pragma unroll
            for (int j = 0; j < 8; ++j) { float v = row[8 * m + j]; r[j] += rnd(v * v); }
        e2[k] = ((r[0] + r[1]) + (r[2] + r[3])) + ((r[4] + r[5]) + (r[6] + r[7]));
    } else if (gid < 12800) {
        int pid = gid - 4608;            // 8192 entries
        int kk = pid >> 10, c4 = (pid >> 6) & 15, lane = pid & 63;
        int code = lane * 8 + kk;
        P4[pid] = *(const float4*)(emb + code * DDIM + c4 * 4);
    }
}

// -------------------- fused distance/argmin + epilogue kernel (R14-identical) -------
// 512 thr = 8 waves x 16 px = 128 px/block. Grid 512 -> 2 blocks/CU, all resident.
// Full 64 KB bf16 codebook staged into LDS ONCE via global_load_lds DMA. Two
// barriers per block. min/2nd-min via v_med3_f32 (R14: -10 us).
__global__ __launch_bounds__(512, 4) void k_dist(
        const float* __restrict__ z_e, const float* __restrict__ emb,
        const bf16x8* __restrict__ Bh, const float* __restrict__ e2g,
        int* __restrict__ idx, int* __restrict__ glist, int* __restrict__ nflag,
        int* __restrict__ counts, float* __restrict__ slots,
        float* __restrict__ out) {
    __shared__ bf16x8 Bs[4096];      // 64 KB: full codebook, fragment order
    __shared__ float e2s[512];
    __shared__ int   hist[512];
    __shared__ int   flist[128];
    __shared__ int   fcnt, fbase;

    int t = threadIdx.x;
    int pxbase = blockIdx.x * 128;
    int batch = pxbase >> 12;
    int p0 = pxbase & 4095;
    const float* zb = z_e + (size_t)batch * (CH * HW) + p0;

    // B-stage: fire 8 async 16B DMAs (in flight during A-loads below)
    #pragma unroll
    for (int i = 0; i < 8; ++i) gl_lds16(Bh + i * 512 + t, Bs + i * 512 + t);

    hist[t] = 0;
    e2s[t] = e2g[t];
    if (t == 0) fcnt = 0;

    int w = t >> 6, lane = t & 63, col = lane & 15, quad = lane >> 4;
    int px = w * 16 + col;

    // A-frags direct from global: px = w*16+col, k = chunk*32 + quad*8 + j
    bf16x8 a0, a1;
    #pragma unroll
    for (int j = 0; j < 8; ++j) {
        a0[j] = f2bf(zb[(quad * 8 + j) * HW + px]);
        a1[j] = f2bf(zb[(32 + quad * 8 + j) * HW + px]);
    }
    __syncthreads();   // barrier #1 (drains the DMA vmcnt)

    float m1[4], m2[4];
    int   i1[4];
    #pragma unroll
    for (int r = 0; r < 4; ++r) { m1[r] = 1e30f; m2[r] = 1e30f; i1[r] = 0; }

    // barrier-free N loop: pure ds_read_b128 + MFMA + med3-select
    #pragma unroll 4
    for (int tn = 0; tn < 32; ++tn) {
        bf16x8 c0 = Bs[tn * 128 + lane];
        bf16x8 c1 = Bs[tn * 128 + 64 + lane];
        float e2v = e2s[tn * 16 + col];
        int n = tn * 16 + col;
        f32x4 acc = {0.f, 0.f, 0.f, 0.f};
        acc = __builtin_amdgcn_mfma_f32_16x16x32_bf16(a0, c0, acc, 0, 0, 0);
        acc = __builtin_amdgcn_mfma_f32_16x16x32_bf16(a1, c1, acc, 0, 0, 0);
        #pragma unroll
        for (int r = 0; r < 4; ++r) {
            float d = fmaf(-2.0f, acc[r], e2v);
            // m2' = med3(d,m1,m2): exact 2nd-min update (R14-verified)
            m2[r] = __builtin_amdgcn_fmed3f(d, m1[r], m2[r]);
            bool c = d < m1[r];
            m1[r] = fminf(d, m1[r]);
            i1[r] = c ? n : i1[r];   // tie keeps earlier n = np first-occurrence
        }
    }

    // merge the 16 cols (xor butterfly -> every lane holds result for px quad*4+r)
    #pragma unroll
    for (int off = 1; off < 16; off <<= 1) {
        #pragma unroll
        for (int r = 0; r < 4; ++r) {
            float om1 = __shfl_xor(m1[r], off);
            float om2 = __shfl_xor(m2[r], off);
            int   oi  = __shfl_xor(i1[r], off);
            if (om1 < m1[r] || (om1 == m1[r] && oi < i1[r])) {
                m2[r] = fminf(m1[r], om2);
                m1[r] = om1;
                i1[r] = oi;
            } else {
                m2[r] = fminf(m2[r], om1);
            }
        }
    }

    // per-pixel outputs: idx, out-idx, LDS histogram + LDS flag list (no global atomics)
    if (col == 0) {
        #pragma unroll
        for (int r = 0; r < 4; ++r) {
            int g = pxbase + w * 16 + quad * 4 + r;
            idx[g] = i1[r];
            out[OUT_IDX + g] = (float)i1[r];
            atomicAdd(&hist[i1[r]], 1);
            if (m2[r] - m1[r] < MARGIN) {
                int pos = atomicAdd(&fcnt, 1);   // LDS atomic
                flist[pos] = g;
            }
        }
    }

    // fused epilogue: z_q_st for this wave's 16 px (z_e is L1/L3-hot), + loss partial
    int q4 = lane & 3;
    int bidx[4];
    #pragma unroll
    for (int j = 0; j < 4; ++j) bidx[j] = __shfl(i1[j], q4 << 4);  // best for px q4*4+j
    const float* zw = zb + w * 16;
    float* ow = out + (size_t)batch * (CH * HW) + p0 + w * 16;
    float lsum = 0.0f;
    #pragma unroll
    for (int it = 0; it < 4; ++it) {
        int c = it * 16 + (lane >> 2);
        float4 ze = *(const float4*)(zw + c * HW + q4 * 4);
        float d0 = emb[bidx[0] * DDIM + c] - ze.x;
        float d1 = emb[bidx[1] * DDIM + c] - ze.y;
        float d2 = emb[bidx[2] * DDIM + c] - ze.z;
        float d3 = emb[bidx[3] * DDIM + c] - ze.w;
        float4 o = {ze.x + d0, ze.y + d1, ze.z + d2, ze.w + d3};
        *(float4*)(ow + c * HW + q4 * 4) = o;
        lsum = lsum + d0 * d0 + d1 * d1 + d2 * d2 + d3 * d3;
    }
    #pragma unroll
    for (int off = 32; off; off >>= 1) lsum += __shfl_down(lsum, off);
    if (lane == 0) atomicAdd(&slots[((blockIdx.x * 8 + w) & 63) * 16], lsum);

    // barrier #2, then flush histogram + flag list (one returning atomic per block)
    __syncthreads();
    int v0 = hist[t];
    if (v0) atomicAdd(&counts[t], v0);
    if (t == 0) fbase = atomicAdd(nflag, fcnt);
    __syncthreads();
    if (t < fcnt) glist[fbase + t] = flist[t];
}

// -------------------- refine + last-block final: full codebook in LDS ---------------
// R14-identical hot path (P4 staged once per block via DMA, numpy-fp32-exact
// re-argmin). Tail: device-scope done-counter; ALL blocks increment (no early-exit
// bypass), last block computes loss/perplexity via atomic reads (R15-verified).
// __launch_bounds__(256) is LOAD-BEARING (R5: VGPR cap 64 -> spill).
__global__ __launch_bounds__(256) void k_refine(
        const float* __restrict__ z_e, const float* __restrict__ emb,
        const float* __restrict__ e2, const float4* __restrict__ P4,
        const int* __restrict__ glist, const int* __restrict__ nflag,
        int* __restrict__ idx, int* __restrict__ counts,
        float* __restrict__ slots, int* __restrict__ done,
        float* __restrict__ out) {
    __shared__ float4 Ps[8192];      // 128 KB: full transposed codebook
    __shared__ float  xs[4][64];     // one x-vector slot per wave
    __shared__ int    islast;
    __shared__ float  ls[4];
    __shared__ float  lsumf;

    int t = threadIdx.x;
    int w = t >> 6, lane = t & 63;
    int n = nflag[0];

    if (blockIdx.x * 4 < n) {        // block-uniform: only blocks with work stage
        #pragma unroll
        for (int i = 0; i < 32; ++i) gl_lds16(P4 + i * 256 + t, Ps + i * 256 + t);
        __syncthreads();             // drains DMA

        // per-lane e2 for codes lane*8..+7 (coalesced float4 pair)
        float4 ea = ((const float4*)e2)[lane * 2];
        float4 eb = ((const float4*)e2)[lane * 2 + 1];
        float e2v[8] = {ea.x, ea.y, ea.z, ea.w, eb.x, eb.y, eb.z, eb.w};

        int wid = blockIdx.x * 4 + w;
        for (int j = wid; j < n; j += 1024) {
            int g = glist[j];                 // wave-uniform scalar load
            int b = g >> 12, p = g & 4095;
            xs[w][lane] = z_e[(size_t)b * (CH * HW) + (size_t)lane * HW + p];
            __threadfence_block();            // wave-lockstep LDS visibility

            const float* xr = xs[w];
            // numpy pairwise ||x||^2 (8 accumulators + tree), broadcast LDS reads
            float r[8];
            #pragma unroll
            for (int jj = 0; jj < 8; ++jj) { float v = xr[jj]; r[jj] = rnd(v * v); }
            #pragma unroll
            for (int mm = 1; mm < 8; ++mm)
                #pragma unroll
                for (int jj = 0; jj < 8; ++jj) { float v = xr[8 * mm + jj]; r[jj] += rnd(v * v); }
            float x2 = ((r[0] + r[1]) + (r[2] + r[3])) + ((r[4] + r[5]) + (r[6] + r[7]));

            float bestd = INFINITY;
            int besti = 1 << 30;
            #pragma unroll
            for (int kk = 0; kk < 8; ++kk) {
                double d0 = 0.0, d1 = 0.0, d2 = 0.0, d3 = 0.0;
                #pragma unroll
                for (int c4 = 0; c4 < 16; ++c4) {
                    float4 xq = *(const float4*)&xr[c4 * 4];         // broadcast
                    float4 ev = Ps[(kk * 16 + c4) * 64 + lane];      // conflict-free
                    d0 = fma((double)xq.x, (double)ev.x, d0);
                    d1 = fma((double)xq.y, (double)ev.y, d1);
                    d2 = fma((double)xq.z, (double)ev.z, d2);
                    d3 = fma((double)xq.w, (double)ev.w, d3);
                }
                float dotf = (float)((d0 + d1) + (d2 + d3));  // ~= sgemm dot
                float tt = x2 + e2v[kk];                      // np fp32 add
                float d = tt - 2.0f * dotf;                   // np fp32 sub
                if (d < bestd) { bestd = d; besti = lane * 8 + kk; }
            }
            #pragma unroll
            for (int off = 32; off; off >>= 1) {
                float od = __shfl_down(bestd, off);
                int   oi = __shfl_down(besti, off);
                if (od < bestd || (od == bestd && oi < besti)) { bestd = od; besti = oi; }
            }
            besti = __shfl(besti, 0);

            int old = idx[g];
            if (besti != old) {
                // patch z_q_st row (lane c = channel c), loss delta, counts, index
                float xc = xr[lane];
                float qn = emb[besti * DDIM + lane];
                float qo = emb[old * DDIM + lane];
                float dn = qn - xc, dold = qo - xc;
                out[(size_t)b * (CH * HW) + (size_t)lane * HW + p] = xc + dn;
                float delta = dn * dn - dold * dold;
                #pragma unroll
                for (int off = 32; off; off >>= 1) delta += __shfl_down(delta, off);
                if (lane == 0) {
                    atomicAdd(&slots[(wid & 63) * 16], delta);
                    atomicAdd(&counts[old], -1);
                    atomicAdd(&counts[besti], 1);
                    idx[g] = besti;
                    out[OUT_IDX + g] = (float)besti;
                }
            }
        }
        __syncthreads();
    }

    // ---- ALL blocks reach here: done-counter, last block finishes scalars ----
    if (t == 0) {
        __threadfence();
        int d = atomicAdd(done, 1);
        islast = (d == (int)gridDim.x - 1);
    }
    __syncthreads();
    if (!islast) return;

    // atomic reads (device-coherent) of counts/slots written by other blocks
    float term = 0.0f;
    #pragma unroll
    for (int h = 0; h < 2; ++h) {
        int c = h * 256 + t;
        float cnt = (float)atomicAdd(&counts[c], 0);
        float pb = cnt * (1.0f / 65536.0f);
        term += pb * logf(pb + 1e-10f);
    }
    #pragma unroll
    for (int off = 32; off; off >>= 1) term += __shfl_down(term, off);
    if (lane == 0) ls[w] = term;
    if (w == 0) {
        float s2 = atomicAdd(&slots[lane * 16], 0.0f);
        #pragma unroll
        for (int off = 32; off; off >>= 1) s2 += __shfl_down(s2, off);
        if (lane == 0) lsumf = s2;
    }
    __syncthreads();
    if (t == 0) {
        float s = ls[0] + ls[1] + ls[2] + ls[3];
        out[OUT_PPL]  = expf(-s);
        out[OUT_LOSS] = 0.25f * (lsumf / (float)NELEM);
    }
}

extern "C" void kernel_launch(void* const* d_in, const int* in_sizes, int n_in,
                              void* d_out, int out_size, void* d_ws, size_t ws_size,
                              hipStream_t stream) {
    const float* z_e = (const float*)d_in[0];
    const float* emb = (const float*)d_in[1];
    float* out = (float*)d_out;
    char* ws = (char*)d_ws;

    // ws layout
    int*    idx    = (int*)(ws);              // 65536 ints   [0, 262144)
    int*    glist  = (int*)(ws + 262144);     // 65536 ints   [262144, 524288)
    float*  e2     = (float*)(ws + 524288);   // 512 floats   [524288, 526336)
    int*    nflag  = (int*)(ws + 526336);     // 1 int (+pad) [526336, 526400)
    int*    counts = (int*)(ws + 526400);     // 512 ints     [526400, 528448)
    float*  slots  = (float*)(ws + 528448);   // 64 x 16 floats [528448, 532544)
    int*    done   = (int*)(ws + 532544);     // 1 int (+pad) [532544, 532608)
    bf16x8* Bh     = (bf16x8*)(ws + 532608);  // 4096 x 16 B = 64 KB
    float4* P4     = (float4*)(ws + 598144);  // 8192 x 16 B = 128 KB

    // zeroing of [526336, 532608) = 1568 ints is done by k_prep block 0
    int* zws = (int*)(ws + 526336);

    k_prep<<<50, 256, 0, stream>>>(emb, e2, Bh, P4, zws);
    k_dist<<<NPIX / 128, 512, 0, stream>>>(z_e, emb, Bh, e2, idx, glist, nflag, counts, slots, out);
    k_refine<<<256, 256, 0, stream>>>(z_e, emb, e2, P4, glist, nflag, idx, counts, slots, done, out);
}

// Round 17
// 129.140 us; speedup vs baseline: 1.5928x; 1.0128x over previous
//
#include <hip/hip_runtime.h>

// Problem constants
#define BATCH 16
#define CH 64          // EMBEDDING_DIM
#define HW 4096        // 64*64
#define NPIX 65536     // BATCH*HW
#define KCODES 512
#define DDIM 64
#define NELEM 4194304  // NPIX*CH

// d_out layout (float32): [z_q_st: NELEM][loss: 1][ppl: 1][indices: NPIX]
#define OUT_LOSS 4194304
#define OUT_PPL  4194305
#define OUT_IDX  4194306

// bf16 gap-error: rms ~4e-5 => 2.2e-4 is ~5.5 sigma; covers np fp32 quantization (7.6e-6)
#define MARGIN 2.2e-4f

typedef short bf16x8 __attribute__((ext_vector_type(8)));
typedef float f32x4  __attribute__((ext_vector_type(4)));

__device__ __forceinline__ float rnd(float s) {   // block fp-contract (numpy-exact squares)
    asm volatile("" : "+v"(s));
    return s;
}
__device__ __forceinline__ short f2bf(float f) {  // RNE fp32->bf16
    unsigned u = __builtin_bit_cast(unsigned, f);
    unsigned r = (u + 0x7fffu + ((u >> 16) & 1u)) >> 16;
    return (short)r;
}
// direct global->LDS DMA, 16B/lane (dest must be wave-uniform base + lane*16)
__device__ __forceinline__ void gl_lds16(const void* g, void* l) {
    __builtin_amdgcn_global_load_lds(
        (const __attribute__((address_space(1))) unsigned*)g,
        (__attribute__((address_space(3))) unsigned*)l, 16, 0, 0);
}

// -------------------- prep: e2 + fragment-ordered bf16 codebook + coalesced fp32 transpose ---
// SEPARATE prep kernel is LOAD-BEARING (R12/R15: fusing it in-block replicates the
// conversion 512x with 64-lines-per-instr access patterns).
// Bh packing: entry = tn*128 + chunk*64 + lane, lane=(q<<4)|i  (HW-verified R4).
// P4 packing (for refine): P4[(kk*16+c4)*64 + lane] = emb[lane*8+kk][c4*4..+3]
__global__ void k_prep(const float* __restrict__ emb, float* __restrict__ e2,
                       bf16x8* __restrict__ Bh, float4* __restrict__ P4) {
    int gid = blockIdx.x * 256 + threadIdx.x;
    if (gid < 4096) {
        int tn = gid >> 7, rem = gid & 127;
        int chunk = (rem >> 6) & 1, q = (rem >> 4) & 3, i = rem & 15;
        int code = tn * 16 + i;
        const float* src = emb + code * DDIM + chunk * 32 + q * 8;
        bf16x8 h;
        #pragma unroll
        for (int j = 0; j < 8; ++j) h[j] = f2bf(src[j]);
        Bh[gid] = h;
    } else if (gid < 4608) {
        int k = gid - 4096;
        const float* row = emb + k * DDIM;
        float r[8];
        #pragma unroll
        for (int j = 0; j < 8; ++j) { float v = row[j]; r[j] = rnd(v * v); }
        #pragma unroll
        for (int m = 1; m < 8; ++m)
            #pragma unroll
            for (int j = 0; j < 8; ++j) { float v = row[8 * m + j]; r[j] += rnd(v * v); }
        e2[k] = ((r[0] + r[1]) + (r[2] + r[3])) + ((r[4] + r[5]) + (r[6] + r[7]));
    } else if (gid < 12800) {
        int pid = gid - 4608;            // 8192 entries
        int kk = pid >> 10, c4 = (pid >> 6) & 15, lane = pid & 63;
        int code = lane * 8 + kk;
        P4[pid] = *(const float4*)(emb + code * DDIM + c4 * 4);
    }
}

// -------------------- fused distance/argmin + epilogue kernel --------------------
// 512 thr = 8 waves x 16 px = 128 px/block. Grid 512 -> 2 blocks/CU, all resident.
// Full 64 KB bf16 codebook staged into LDS ONCE via global_load_lds DMA. Two
// barriers per block. min/2nd-min via v_med3_f32: 5 VALU/eval (R14: -10 us).
__global__ __launch_bounds__(512, 4) void k_dist(
        const float* __restrict__ z_e, const float* __restrict__ emb,
        const bf16x8* __restrict__ Bh, const float* __restrict__ e2g,
        int* __restrict__ idx, int* __restrict__ glist, int* __restrict__ nflag,
        int* __restrict__ counts, float* __restrict__ slots,
        float* __restrict__ out) {
    __shared__ bf16x8 Bs[4096];      // 64 KB: full codebook, fragment order
    __shared__ float e2s[512];
    __shared__ int   hist[512];
    __shared__ int   flist[128];
    __shared__ int   fcnt, fbase;

    int t = threadIdx.x;
    int pxbase = blockIdx.x * 128;
    int batch = pxbase >> 12;
    int p0 = pxbase & 4095;
    const float* zb = z_e + (size_t)batch * (CH * HW) + p0;

    // B-stage: fire 8 async 16B DMAs (in flight during A-loads below)
    #pragma unroll
    for (int i = 0; i < 8; ++i) gl_lds16(Bh + i * 512 + t, Bs + i * 512 + t);

    hist[t] = 0;
    e2s[t] = e2g[t];
    if (t == 0) fcnt = 0;

    int w = t >> 6, lane = t & 63, col = lane & 15, quad = lane >> 4;
    int px = w * 16 + col;

    // A-frags direct from global: px = w*16+col, k = chunk*32 + quad*8 + j
    bf16x8 a0, a1;
    #pragma unroll
    for (int j = 0; j < 8; ++j) {
        a0[j] = f2bf(zb[(quad * 8 + j) * HW + px]);
        a1[j] = f2bf(zb[(32 + quad * 8 + j) * HW + px]);
    }
    __syncthreads();   // barrier #1 (drains the DMA vmcnt)

    float m1[4], m2[4];
    int   i1[4];
    #pragma unroll
    for (int r = 0; r < 4; ++r) { m1[r] = 1e30f; m2[r] = 1e30f; i1[r] = 0; }

    // barrier-free N loop: pure ds_read_b128 + MFMA + med3-select
    #pragma unroll 4
    for (int tn = 0; tn < 32; ++tn) {
        bf16x8 c0 = Bs[tn * 128 + lane];
        bf16x8 c1 = Bs[tn * 128 + 64 + lane];
        float e2v = e2s[tn * 16 + col];
        int n = tn * 16 + col;
        f32x4 acc = {0.f, 0.f, 0.f, 0.f};
        acc = __builtin_amdgcn_mfma_f32_16x16x32_bf16(a0, c0, acc, 0, 0, 0);
        acc = __builtin_amdgcn_mfma_f32_16x16x32_bf16(a1, c1, acc, 0, 0, 0);
        #pragma unroll
        for (int r = 0; r < 4; ++r) {
            float d = fmaf(-2.0f, acc[r], e2v);
            // m2' = med3(d,m1,m2): exact 2nd-min update (R14-verified)
            m2[r] = __builtin_amdgcn_fmed3f(d, m1[r], m2[r]);
            bool c = d < m1[r];
            m1[r] = fminf(d, m1[r]);
            i1[r] = c ? n : i1[r];   // tie keeps earlier n = np first-occurrence
        }
    }

    // merge the 16 cols (xor butterfly -> every lane holds result for px quad*4+r)
    #pragma unroll
    for (int off = 1; off < 16; off <<= 1) {
        #pragma unroll
        for (int r = 0; r < 4; ++r) {
            float om1 = __shfl_xor(m1[r], off);
            float om2 = __shfl_xor(m2[r], off);
            int   oi  = __shfl_xor(i1[r], off);
            if (om1 < m1[r] || (om1 == m1[r] && oi < i1[r])) {
                m2[r] = fminf(m1[r], om2);
                m1[r] = om1;
                i1[r] = oi;
            } else {
                m2[r] = fminf(m2[r], om1);
            }
        }
    }

    // per-pixel outputs: idx, out-idx, LDS histogram + LDS flag list (no global atomics)
    if (col == 0) {
        #pragma unroll
        for (int r = 0; r < 4; ++r) {
            int g = pxbase + w * 16 + quad * 4 + r;
            idx[g] = i1[r];
            out[OUT_IDX + g] = (float)i1[r];
            atomicAdd(&hist[i1[r]], 1);
            if (m2[r] - m1[r] < MARGIN) {
                int pos = atomicAdd(&fcnt, 1);   // LDS atomic
                flist[pos] = g;
            }
        }
    }

    // fused epilogue: z_q_st for this wave's 16 px (z_e is L1/L3-hot), + loss partial
    int q4 = lane & 3;
    int bidx[4];
    #pragma unroll
    for (int j = 0; j < 4; ++j) bidx[j] = __shfl(i1[j], q4 << 4);  // best for px q4*4+j
    const float* zw = zb + w * 16;
    float* ow = out + (size_t)batch * (CH * HW) + p0 + w * 16;
    float lsum = 0.0f;
    #pragma unroll
    for (int it = 0; it < 4; ++it) {
        int c = it * 16 + (lane >> 2);
        float4 ze = *(const float4*)(zw + c * HW + q4 * 4);
        float d0 = emb[bidx[0] * DDIM + c] - ze.x;
        float d1 = emb[bidx[1] * DDIM + c] - ze.y;
        float d2 = emb[bidx[2] * DDIM + c] - ze.z;
        float d3 = emb[bidx[3] * DDIM + c] - ze.w;
        float4 o = {ze.x + d0, ze.y + d1, ze.z + d2, ze.w + d3};
        *(float4*)(ow + c * HW + q4 * 4) = o;
        lsum = lsum + d0 * d0 + d1 * d1 + d2 * d2 + d3 * d3;
    }
    #pragma unroll
    for (int off = 32; off; off >>= 1) lsum += __shfl_down(lsum, off);
    if (lane == 0) atomicAdd(&slots[((blockIdx.x * 8 + w) & 63) * 16], lsum);

    // barrier #2, then flush histogram + flag list (one returning atomic per block)
    __syncthreads();
    int v0 = hist[t];
    if (v0) atomicAdd(&counts[t], v0);
    if (t == 0) fbase = atomicAdd(nflag, fcnt);
    __syncthreads();
    if (t < fcnt) glist[fbase + t] = flist[t];
}

// -------------------- refine: full codebook in LDS, numpy-fp32-exact re-argmin ------
// Full 128 KB fp32 transposed codebook staged ONCE per block via global_load_lds
// (R12 lesson: streaming it per-flag from L2 = 268 MB fetch = 350 us). One barrier,
// then each wave grid-strides flags barrier-free. Numerics identical to the
// R9-R14-verified path.  __launch_bounds__(256) is LOAD-BEARING (R5: VGPR cap 64
// -> spill -> 90 MB scratch traffic).
__global__ __launch_bounds__(256) void k_refine(
        const float* __restrict__ z_e, const float* __restrict__ emb,
        const float* __restrict__ e2, const float4* __restrict__ P4,
        const int* __restrict__ glist, const int* __restrict__ nflag,
        int* __restrict__ idx, int* __restrict__ counts,
        float* __restrict__ slots, float* __restrict__ out) {
    __shared__ float4 Ps[8192];      // 128 KB: full transposed codebook
    __shared__ float  xs[4][64];     // one x-vector slot per wave

    int t = threadIdx.x;
    int w = t >> 6, lane = t & 63;
    int n = nflag[0];
    if (blockIdx.x >= n) return;     // block-uniform early exit (handles n==0)

    #pragma unroll
    for (int i = 0; i < 32; ++i) gl_lds16(P4 + i * 256 + t, Ps + i * 256 + t);
    __syncthreads();                 // the only barrier (drains DMA)

    // per-lane e2 for codes lane*8..+7 (coalesced float4 pair)
    float4 ea = ((const float4*)e2)[lane * 2];
    float4 eb = ((const float4*)e2)[lane * 2 + 1];
    float e2v[8] = {ea.x, ea.y, ea.z, ea.w, eb.x, eb.y, eb.z, eb.w};

    int wid = blockIdx.x * 4 + w;
    for (int j = wid; j < n; j += 1024) {
        int g = glist[j];                 // wave-uniform scalar load
        int b = g >> 12, p = g & 4095;
        xs[w][lane] = z_e[(size_t)b * (CH * HW) + (size_t)lane * HW + p];
        __threadfence_block();            // wave-lockstep LDS visibility

        const float* xr = xs[w];
        // numpy pairwise ||x||^2 (8 accumulators + tree), broadcast LDS reads
        float r[8];
        #pragma unroll
        for (int jj = 0; jj < 8; ++jj) { float v = xr[jj]; r[jj] = rnd(v * v); }
        #pragma unroll
        for (int mm = 1; mm < 8; ++mm)
            #pragma unroll
            for (int jj = 0; jj < 8; ++jj) { float v = xr[8 * mm + jj]; r[jj] += rnd(v * v); }
        float x2 = ((r[0] + r[1]) + (r[2] + r[3])) + ((r[4] + r[5]) + (r[6] + r[7]));

        float bestd = INFINITY;
        int besti = 1 << 30;
        #pragma unroll
        for (int kk = 0; kk < 8; ++kk) {
            double d0 = 0.0, d1 = 0.0, d2 = 0.0, d3 = 0.0;
            #pragma unroll
            for (int c4 = 0; c4 < 16; ++c4) {
                float4 xq = *(const float4*)&xr[c4 * 4];         // broadcast
                float4 ev = Ps[(kk * 16 + c4) * 64 + lane];      // per-lane, conflict-free
                d0 = fma((double)xq.x, (double)ev.x, d0);
                d1 = fma((double)xq.y, (double)ev.y, d1);
                d2 = fma((double)xq.z, (double)ev.z, d2);
                d3 = fma((double)xq.w, (double)ev.w, d3);
            }
            float dotf = (float)((d0 + d1) + (d2 + d3));  // ~= sgemm dot
            float tt = x2 + e2v[kk];                      // np fp32 add
            float d = tt - 2.0f * dotf;                   // np fp32 sub
            if (d < bestd) { bestd = d; besti = lane * 8 + kk; }
        }
        #pragma unroll
        for (int off = 32; off; off >>= 1) {
            float od = __shfl_down(bestd, off);
            int   oi = __shfl_down(besti, off);
            if (od < bestd || (od == bestd && oi < besti)) { bestd = od; besti = oi; }
        }
        besti = __shfl(besti, 0);

        int old = idx[g];
        if (besti != old) {
            // patch z_q_st row (lane c = channel c), loss delta, counts, index
            float xc = xr[lane];
            float qn = emb[besti * DDIM + lane];
            float qo = emb[old * DDIM + lane];
            float dn = qn - xc, dold = qo - xc;
            out[(size_t)b * (CH * HW) + (size_t)lane * HW + p] = xc + dn;
            float delta = dn * dn - dold * dold;
            #pragma unroll
            for (int off = 32; off; off >>= 1) delta += __shfl_down(delta, off);
            if (lane == 0) {
                atomicAdd(&slots[(wid & 63) * 16], delta);
                atomicAdd(&counts[old], -1);
                atomicAdd(&counts[besti], 1);
                idx[g] = besti;
                out[OUT_IDX + g] = (float)besti;
            }
        }
    }
}

// -------------------- final scalars: loss, perplexity --------------------
__global__ void k_final(const int* __restrict__ counts,
                        const float* __restrict__ slots,
                        float* __restrict__ out) {
    int t = threadIdx.x;  // 512 threads, 1 block
    float cnt = (float)counts[t];
    float pb = cnt * (1.0f / 65536.0f);
    float term = pb * logf(pb + 1e-10f);
    #pragma unroll
    for (int off = 32; off; off >>= 1) term += __shfl_down(term, off);
    __shared__ float ls[8];
    __shared__ float lsum;
    int lane = t & 63, w = t >> 6;
    if (lane == 0) ls[w] = term;
    if (w == 0) {                               // wave 0 reduces the 64 loss slots
        float s2 = slots[lane * 16];
        #pragma unroll
        for (int off = 32; off; off >>= 1) s2 += __shfl_down(s2, off);
        if (lane == 0) lsum = s2;
    }
    __syncthreads();
    if (t == 0) {
        float s = 0.0f;
        #pragma unroll
        for (int i = 0; i < 8; ++i) s += ls[i];
        out[OUT_PPL]  = expf(-s);
        out[OUT_LOSS] = 0.25f * (lsum / (float)NELEM);
    }
}

extern "C" void kernel_launch(void* const* d_in, const int* in_sizes, int n_in,
                              void* d_out, int out_size, void* d_ws, size_t ws_size,
                              hipStream_t stream) {
    const float* z_e = (const float*)d_in[0];
    const float* emb = (const float*)d_in[1];
    float* out = (float*)d_out;
    char* ws = (char*)d_ws;

    // ws layout
    int*    idx    = (int*)(ws);              // 65536 ints   [0, 262144)
    int*    glist  = (int*)(ws + 262144);     // 65536 ints   [262144, 524288)
    float*  e2     = (float*)(ws + 524288);   // 512 floats   [524288, 526336)
    int*    nflag  = (int*)(ws + 526336);     // 1 int (+pad) [526336, 526400)
    int*    counts = (int*)(ws + 526400);     // 512 ints     [526400, 528448)
    float*  slots  = (float*)(ws + 528448);   // 64 x 16 floats [528448, 532544)
    bf16x8* Bh     = (bf16x8*)(ws + 532544);  // 4096 x 16 B = 64 KB
    float4* P4     = (float4*)(ws + 598080);  // 8192 x 16 B = 128 KB [598080, 729152)

    // zero nflag + counts + slots (ws is poisoned 0xAA before every timed launch)
    hipMemsetAsync(ws + 526336, 0, 532544 - 526336, stream);

    k_prep<<<50, 256, 0, stream>>>(emb, e2, Bh, P4);
    k_dist<<<NPIX / 128, 512, 0, stream>>>(z_e, emb, Bh, e2, idx, glist, nflag, counts, slots, out);
    k_refine<<<256, 256, 0, stream>>>(z_e, emb, e2, P4, glist, nflag, idx, counts, slots, out);
    k_final<<<1, 512, 0, stream>>>(counts, slots, out);
}